// Round 22
// baseline (139.954 us; speedup 1.0000x reference)
//
#include <hip/hip_runtime.h>

// GCN 3-layer, R22 = R21 with:
//  1) fused_l2l3 at 512 thr / 8 waves sharing Wl (LDS/wave 5.4K->3.3K;
//     R17's regression was 16-wave coupling; 8-wave untested midpoint).
//  2) bucketAF stages its tmp chunk in LDS (<=5120 edges + global fallback)
//     -- kills the cold cross-XCD second pass.

#define BKSH 8                      // 256 nodes per bucket
#define EPB  4096                   // edges per scatter block
#define EMAXB 5120                  // bucket-chunk LDS stage cap (mean 4096, sigma~64)

__device__ __forceinline__ float rlane(float v, int l) {
    return __int_as_float(__builtin_amdgcn_readlane(__float_as_int(v), l));
}
__device__ __forceinline__ int rlane_i(int v, int l) {
    return __builtin_amdgcn_readlane(v, l);
}

// ---- per-block bucket histogram ----
__global__ void bhist(const int* __restrict__ dst, int* __restrict__ ghist,
                      int E, int NBK, int BLK) {
    __shared__ int h[512];
    int t = threadIdx.x, b = blockIdx.x;
    for (int i = t; i < NBK; i += 256) h[i] = 0;
    __syncthreads();
    int base = b * EPB;
    #pragma unroll
    for (int i = 0; i < 16; ++i) {
        int e = base + i * 256 + t;
        if (e < E) atomicAdd(&h[dst[e] >> BKSH], 1);
    }
    __syncthreads();
    for (int i = t; i < NBK; i += 256) ghist[(size_t)i * BLK + b] = h[i];
}

// ---- exclusive scan phases (block-sum add folded into readers) ----
__global__ void gscan1(const int* __restrict__ in, int* __restrict__ out,
                       int* __restrict__ bsums, int M) {
    __shared__ int tmp[256];
    int i = blockIdx.x * 256 + threadIdx.x;
    int v = (i < M) ? in[i] : 0;
    tmp[threadIdx.x] = v; __syncthreads();
    for (int off = 1; off < 256; off <<= 1) {
        int t = (threadIdx.x >= off) ? tmp[threadIdx.x - off] : 0;
        __syncthreads();
        tmp[threadIdx.x] += t;
        __syncthreads();
    }
    if (i < M) out[i] = tmp[threadIdx.x] - v;
    if (threadIdx.x == 255) bsums[blockIdx.x] = tmp[255];
}

__global__ void gscan2(int* __restrict__ bsums, int nb) {   // 1 block, 1024 thr
    __shared__ int tmp[1024];
    int v = (threadIdx.x < nb) ? bsums[threadIdx.x] : 0;
    tmp[threadIdx.x] = v; __syncthreads();
    for (int off = 1; off < 1024; off <<= 1) {
        int t = (threadIdx.x >= off) ? tmp[threadIdx.x - off] : 0;
        __syncthreads();
        tmp[threadIdx.x] += t;
        __syncthreads();
    }
    if (threadIdx.x < nb) bsums[threadIdx.x] = tmp[threadIdx.x] - v;
}

// ---- scatter PACKED edges into bucket-sorted tmp ----
__global__ void bscatter(const int* __restrict__ src, const int* __restrict__ dst,
                         const int* __restrict__ goff, const int* __restrict__ gbsums,
                         unsigned* __restrict__ tmp, int E, int NBK, int BLK) {
    __shared__ int off[512];
    int t = threadIdx.x, b = blockIdx.x;
    for (int i = t; i < NBK; i += 256) {
        size_t m = (size_t)i * BLK + b;
        off[i] = goff[m] + gbsums[m >> 8];
    }
    __syncthreads();
    int base = b * EPB;
    #pragma unroll
    for (int i = 0; i < 16; ++i) {
        int e = base + i * 256 + t;
        if (e < E) {
            int d = dst[e];
            int p = atomicAdd(&off[d >> BKSH], 1);   // LDS-local
            tmp[p] = ((unsigned)src[e] << 8) | (unsigned)(d & 255);
        }
    }
}

// ---- per-bucket: count + LDS scan -> rowptr,dinv,xd4; place ewsrc ----
// Chunk staged in LDS (cap EMAXB, global fallback) -> single global read.
__global__ void bucketAF(const unsigned* __restrict__ tmp, const int* __restrict__ goff,
                         const int* __restrict__ gbsums, const float* __restrict__ x,
                         int* __restrict__ rowptr, float* __restrict__ dinv,
                         float4* __restrict__ xd4, int* __restrict__ ewsrc,
                         int N, int NBK, int BLK, int E) {
    __shared__ int lc[256], sc[256], rbase[256];
    __shared__ unsigned echunk[EMAXB];
    int b = blockIdx.x, t = threadIdx.x;
    lc[t] = 0;
    size_t m0 = (size_t)b * BLK;
    int p0 = goff[m0] + gbsums[m0 >> 8];
    int p1 = E;
    if (b + 1 < NBK) { size_t m1 = (size_t)(b + 1) * BLK; p1 = goff[m1] + gbsums[m1 >> 8]; }
    int len = p1 - p0;
    int stage = len < EMAXB ? len : EMAXB;
    for (int i = t; i < stage; i += 256) echunk[i] = tmp[p0 + i];   // coalesced
    __syncthreads();
    for (int i = t; i < len; i += 256) {
        unsigned e = (i < stage) ? echunk[i] : tmp[p0 + i];
        atomicAdd(&lc[e & 255u], 1);
    }
    __syncthreads();
    int v = lc[t];
    sc[t] = v; __syncthreads();
    for (int off = 1; off < 256; off <<= 1) {
        int tv = (t >= off) ? sc[t - off] : 0;
        __syncthreads();
        sc[t] += tv;
        __syncthreads();
    }
    int rb = p0 + (sc[t] - v);
    rbase[t] = rb;
    int node = (b << BKSH) + t;
    if (node < N) {
        rowptr[node] = rb;
        float dvv = rsqrtf((float)(v + 1));
        dinv[node] = dvv;
        xd4[node]  = make_float4(dvv * x[3*node], dvv * x[3*node+1],
                                 dvv * x[3*node+2], 0.f);
    }
    if (b == 0 && t == 0) rowptr[N] = E;
    lc[t] = 0;                        // reuse as fill counters
    __syncthreads();
    for (int i = t; i < len; i += 256) {
        unsigned e = (i < stage) ? echunk[i] : tmp[p0 + i];
        int dl = (int)(e & 255u);
        int pos = rbase[dl] + atomicAdd(&lc[dl], 1);
        ewsrc[pos] = (int)(e >> 8);
    }
}

// ---- a1[n] = {dinv*(sum xd[s] + xd[n]), dinv}; 16-lane group per node ----
__global__ void agg3w(const int* __restrict__ ewsrc, const int* __restrict__ rowptr,
                      const float* __restrict__ dinv, const float4* __restrict__ xd4,
                      float4* __restrict__ a1, int N) {
    int g   = (blockIdx.x * blockDim.x + threadIdx.x) >> 4;
    int sub = threadIdx.x & 15;
    if (g >= N) return;
    int p0 = rowptr[g], p1 = rowptr[g+1];
    float ax = 0.f, ay = 0.f, az = 0.f;
    for (int p = p0 + sub; p < p1; p += 16) {
        float4 xs = xd4[ewsrc[p]];
        ax += xs.x; ay += xs.y; az += xs.z;
    }
    #pragma unroll
    for (int off = 8; off; off >>= 1) {
        ax += __shfl_down(ax, off, 16);
        ay += __shfl_down(ay, off, 16);
        az += __shfl_down(az, off, 16);
    }
    if (sub == 0) {
        float dv = dinv[g];
        float4 xn = xd4[g];
        a1[g] = make_float4(dv * (ax + xn.x), dv * (ay + xn.y),
                            dv * (az + xn.z), dv);
    }
}

// wc[k] = W3[k][:] @ Wh; wc[64] = b3 @ Wh + bh
__global__ void fold_head(const float* __restrict__ W3, const float* __restrict__ b3,
                          const float* __restrict__ Wh, const float* __restrict__ bh,
                          float* __restrict__ wc) {
    int k = threadIdx.x;              // 64
    float acc = 0.0f;
    for (int f = 0; f < 64; f++) acc += W3[k*64+f] * Wh[f];
    wc[k] = acc;
    if (k == 0) {
        float bb = bh[0];
        for (int f = 0; f < 64; f++) bb += b3[f] * Wh[f];
        wc[64] = bb;
    }
}

// zz[n] = dinv_n * relu( a2 @ W2 + b2 ) @ wc,
//   a2 = dinv_n*(dinv_n*relu(h1_n) + sum dinv_s*relu(h1_s)).
// 512 thr / 8 waves sharing Wl; per-wave structure = R21.
__global__ void fused_l2l3(const int* __restrict__ ewsrc, const int* __restrict__ rowptr,
                           const float4* __restrict__ a1, const float* __restrict__ W1,
                           const float* __restrict__ b1, const float* __restrict__ W2,
                           const float* __restrict__ b2, const float* __restrict__ wc,
                           float* __restrict__ zz, int N, int E) {
    __shared__ float  Wl[64*64];
    __shared__ float4 pay[8][64];
    __shared__ float  a2buf[8][64];
    const int tid = threadIdx.x;        // 512
    for (int i = tid; i < 4096; i += 512) Wl[i] = W2[i];
    const int lane = tid & 63;
    const int wv   = tid >> 6;          // 0..7
    const float w10 = W1[lane], w11 = W1[64+lane], w12 = W1[128+lane];
    const float b1f = b1[lane], b2f = b2[lane], wcf = wc[lane];
    const int NPW = 8;
    const int n0 = (blockIdx.x * 8 + wv) * NPW;
    int   rpl = rowptr[min(n0 + lane, N)];         // lanes 0..9 used
    float4 sg = a1[min(n0 + lane, N - 1)];         // lanes 0..7 (self; .w=dinv)
    __syncthreads();
    if (n0 >= N) return;                           // after barrier: safe
    int NPWv = N - n0; if (NPWv > NPW) NPWv = NPW; // valid nodes (SGPR)
    // prologue: chunk0 of node 0 into regs
    int p0c = rlane_i(rpl, 0), p1c = rlane_i(rpl, 1);
    float4 g_c = make_float4(0.f, 0.f, 0.f, 0.f);
    if (p0c < p1c) {
        int pidx = p0c + lane; if (pidx >= p1c) pidx = p1c - 1;
        g_c = a1[ewsrc[pidx]];
    }
    for (int cur = 0; cur < NPWv; ++cur) {
        int p0 = p0c, p1 = p1c;
        pay[wv][lane] = g_c;                       // ds_write_b128
        // prefetch node cur+1's chunk0 (VMEM hidden under consume+epilogue)
        if (cur + 1 < NPWv) {
            p0c = rlane_i(rpl, cur + 1);
            p1c = rlane_i(rpl, cur + 2);
            if (p0c < p1c) {
                int pidx = p0c + lane; if (pidx >= p1c) pidx = p1c - 1;
                g_c = a1[ewsrc[pidx]];
            }
        }
        // self term (-> acc0); 4 independent partial accumulators
        float sx = rlane(sg.x, cur), sy = rlane(sg.y, cur);
        float sz2 = rlane(sg.z, cur), sw = rlane(sg.w, cur);   // sw = dinv_d
        float ts = fmaf(sz2, w12, fmaf(sy, w11, fmaf(sx, w10, b1f)));
        float acc0 = sw * fmaxf(ts, 0.f);
        float acc1 = 0.f, acc2 = 0.f, acc3 = 0.f;
        // consume chunk0 from LDS (uniform ds_read_b128 broadcast)
        {
            int m = p1 - p0; if (m > 64) m = 64;   // uniform (SGPR)
            const float4* pp = (const float4*)&pay[wv][0];
            int j = 0;
            for (; j + 3 < m; j += 4) {
                float4 P0 = pp[j], P1 = pp[j+1], P2 = pp[j+2], P3 = pp[j+3];
                float t0 = fmaf(P0.z, w12, fmaf(P0.y, w11, fmaf(P0.x, w10, b1f)));
                float t1 = fmaf(P1.z, w12, fmaf(P1.y, w11, fmaf(P1.x, w10, b1f)));
                float t2 = fmaf(P2.z, w12, fmaf(P2.y, w11, fmaf(P2.x, w10, b1f)));
                float t3 = fmaf(P3.z, w12, fmaf(P3.y, w11, fmaf(P3.x, w10, b1f)));
                acc0 = fmaf(P0.w, fmaxf(t0, 0.f), acc0);
                acc1 = fmaf(P1.w, fmaxf(t1, 0.f), acc1);
                acc2 = fmaf(P2.w, fmaxf(t2, 0.f), acc2);
                acc3 = fmaf(P3.w, fmaxf(t3, 0.f), acc3);
            }
            for (; j < m; ++j) {
                float4 P = pp[j];
                float tt = fmaf(P.z, w12, fmaf(P.y, w11, fmaf(P.x, w10, b1f)));
                acc1 = fmaf(P.w, fmaxf(tt, 0.f), acc1);
            }
        }
        // rare extra chunks (deg > 64): direct load + re-stage + consume
        for (int pc = p0 + 64; pc < p1; pc += 64) {
            int pidx = pc + lane; if (pidx >= p1) pidx = p1 - 1;
            float4 g2 = a1[ewsrc[pidx]];
            pay[wv][lane] = g2;                    // prior reads done (in-order wave)
            int m2 = p1 - pc; if (m2 > 64) m2 = 64;
            const float4* pp = (const float4*)&pay[wv][0];
            for (int j = 0; j < m2; ++j) {
                float4 P = pp[j];
                float tt = fmaf(P.z, w12, fmaf(P.y, w11, fmaf(P.x, w10, b1f)));
                acc2 = fmaf(P.w, fmaxf(tt, 0.f), acc2);
            }
        }
        float acc = ((acc0 + acc1) + (acc2 + acc3)) * sw;      // a2 = dinv_d*(...)
        // per-node epilogue with 4 independent partials
        a2buf[wv][lane] = acc;
        float ha = 0.f, hb = 0.f, hc = 0.f, hd = 0.f;
        const float4* a4 = (const float4*)&a2buf[wv][0];
        #pragma unroll
        for (int k4 = 0; k4 < 16; ++k4) {
            float4 a = a4[k4];                     // uniform broadcast read
            ha = fmaf(a.x, Wl[(4*k4+0)*64 + lane], ha);
            hb = fmaf(a.y, Wl[(4*k4+1)*64 + lane], hb);
            hc = fmaf(a.z, Wl[(4*k4+2)*64 + lane], hc);
            hd = fmaf(a.w, Wl[(4*k4+3)*64 + lane], hd);
        }
        float h = b2f + ((ha + hb) + (hc + hd));
        float v = fmaxf(h, 0.f) * wcf;
        #pragma unroll
        for (int off = 32; off; off >>= 1) v += __shfl_down(v, off);
        if (lane == 0) zz[n0 + cur] = sw * v;      // zz = dinv_n * z
    }
}

// out[d] = dinv_d*(zz[d] + sum_e zz[src]) + c; 16-lane group per node
__global__ void final_wave(const float* __restrict__ zz, const int* __restrict__ ewsrc,
                           const int* __restrict__ rowptr, const float* __restrict__ dinv,
                           const float* __restrict__ wc, float* __restrict__ out, int N) {
    int g   = (blockIdx.x * blockDim.x + threadIdx.x) >> 4;
    int sub = threadIdx.x & 15;
    if (g >= N) return;
    int p0 = rowptr[g], p1 = rowptr[g+1];
    float acc = 0.f;
    for (int p = p0 + sub; p < p1; p += 16) {
        acc += zz[ewsrc[p]];
    }
    #pragma unroll
    for (int off = 8; off; off >>= 1) acc += __shfl_down(acc, off, 16);
    if (sub == 0) {
        out[g] = fmaf(dinv[g], zz[g] + acc, wc[64]);
    }
}

extern "C" void kernel_launch(void* const* d_in, const int* in_sizes, int n_in,
                              void* d_out, int out_size, void* d_ws, size_t ws_size,
                              hipStream_t stream) {
    const float* x   = (const float*)d_in[0];
    const int*   ei  = (const int*)d_in[1];
    const float* W1  = (const float*)d_in[2];
    const float* b1  = (const float*)d_in[3];
    const float* W2  = (const float*)d_in[4];
    const float* b2  = (const float*)d_in[5];
    const float* W3  = (const float*)d_in[6];
    const float* b3  = (const float*)d_in[7];
    const float* Wh  = (const float*)d_in[8];
    const float* bh  = (const float*)d_in[9];
    float* logits = (float*)d_out;

    const int N = in_sizes[0] / 3;
    const int E = in_sizes[1] / 2;
    const int* src = ei;
    const int* dst = ei + E;

    const int NBK = (N + 255) >> BKSH;            // 391 buckets
    const int BLK = (E + EPB - 1) / EPB;          // 391 scatter blocks
    const int M   = NBK * BLK;

    float* base = (float*)d_ws;
    size_t o = 0;
    float*    dinv   = base + o; o += (size_t)N;
    o = (o + 3) & ~(size_t)3;
    float4*   a1     = (float4*)(base + o); o += (size_t)4*N;
    float4*   xd4    = (float4*)(base + o); o += (size_t)4*N;
    int*      rowptr = (int*)(base + o); o += (size_t)N + 1;
    int*      gbsums = (int*)(base + o); o += 1024;
    int*      ewsrc  = (int*)(base + o); o += (size_t)E;
    unsigned* tmpp   = (unsigned*)(base + o); o += (size_t)E;
    float*    zz     = base + o; o += (size_t)N;
    float*    wc     = base + o; o += 65;
    int*      ghist  = (int*)(base + o); o += (size_t)M;
    int*      goff   = (int*)(base + o); o += (size_t)M;

    const int BS = 256;
    int gM   = (M + BS - 1) / BS;
    int g16  = ((size_t)N * 16 + BS - 1) / BS;
    int gFU  = (N + 63) / 64;                     // 8 waves x 8 nodes per block

    bhist    <<<BLK, BS, 0, stream>>>(dst, ghist, E, NBK, BLK);
    gscan1   <<<gM,  BS, 0, stream>>>(ghist, goff, gbsums, M);
    gscan2   <<<1, 1024, 0, stream>>>(gbsums, gM);
    bscatter <<<BLK, BS, 0, stream>>>(src, dst, goff, gbsums, tmpp, E, NBK, BLK);
    bucketAF <<<NBK, BS, 0, stream>>>(tmpp, goff, gbsums, x, rowptr, dinv, xd4, ewsrc, N, NBK, BLK, E);
    agg3w    <<<g16, BS, 0, stream>>>(ewsrc, rowptr, dinv, xd4, a1, N);

    fold_head  <<<1, 64, 0, stream>>>(W3, b3, Wh, bh, wc);
    fused_l2l3 <<<gFU, 512, 0, stream>>>(ewsrc, rowptr, a1, W1, b1, W2, b2, wc, zz, N, E);
    final_wave <<<g16, BS, 0, stream>>>(zz, ewsrc, rowptr, dinv, wc, logits, N);
}

// Round 23
// 131.920 us; speedup vs baseline: 1.0609x; 1.0609x over previous
//
#include <hip/hip_runtime.h>

// GCN 3-layer, R23 = R21 build (fold_head merged into agg3w) + fused_l2l3
// restructured to STAGE-ALL-THEN-CONSUME:
//  wave's 8 nodes own contiguous edges [P0,P8) (mean 128). Stage the whole
//  span up-front (<=192, overflow -> per-chunk restage; safe since consume is
//  monotonic), then consume all nodes from LDS. Payload-load lane utilization
//  25%->100%; VMEM issues/wave 16->~6; one latency wait instead of 8.

#define BKSH 8                      // 256 nodes per bucket
#define EPB  4096                   // edges per scatter block
#define PAYCAP 192                  // staged-span cap (mean 128, sd ~11)

__device__ __forceinline__ float rlane(float v, int l) {
    return __int_as_float(__builtin_amdgcn_readlane(__float_as_int(v), l));
}
__device__ __forceinline__ int rlane_i(int v, int l) {
    return __builtin_amdgcn_readlane(v, l);
}

// ---- per-block bucket histogram ----
__global__ void bhist(const int* __restrict__ dst, int* __restrict__ ghist,
                      int E, int NBK, int BLK) {
    __shared__ int h[512];
    int t = threadIdx.x, b = blockIdx.x;
    for (int i = t; i < NBK; i += 256) h[i] = 0;
    __syncthreads();
    int base = b * EPB;
    #pragma unroll
    for (int i = 0; i < 16; ++i) {
        int e = base + i * 256 + t;
        if (e < E) atomicAdd(&h[dst[e] >> BKSH], 1);
    }
    __syncthreads();
    for (int i = t; i < NBK; i += 256) ghist[(size_t)i * BLK + b] = h[i];
}

// ---- exclusive scan phases (block-sum add folded into readers) ----
__global__ void gscan1(const int* __restrict__ in, int* __restrict__ out,
                       int* __restrict__ bsums, int M) {
    __shared__ int tmp[256];
    int i = blockIdx.x * 256 + threadIdx.x;
    int v = (i < M) ? in[i] : 0;
    tmp[threadIdx.x] = v; __syncthreads();
    for (int off = 1; off < 256; off <<= 1) {
        int t = (threadIdx.x >= off) ? tmp[threadIdx.x - off] : 0;
        __syncthreads();
        tmp[threadIdx.x] += t;
        __syncthreads();
    }
    if (i < M) out[i] = tmp[threadIdx.x] - v;
    if (threadIdx.x == 255) bsums[blockIdx.x] = tmp[255];
}

__global__ void gscan2(int* __restrict__ bsums, int nb) {   // 1 block, 1024 thr
    __shared__ int tmp[1024];
    int v = (threadIdx.x < nb) ? bsums[threadIdx.x] : 0;
    tmp[threadIdx.x] = v; __syncthreads();
    for (int off = 1; off < 1024; off <<= 1) {
        int t = (threadIdx.x >= off) ? tmp[threadIdx.x - off] : 0;
        __syncthreads();
        tmp[threadIdx.x] += t;
        __syncthreads();
    }
    if (threadIdx.x < nb) bsums[threadIdx.x] = tmp[threadIdx.x] - v;
}

// ---- scatter PACKED edges into bucket-sorted tmp ----
__global__ void bscatter(const int* __restrict__ src, const int* __restrict__ dst,
                         const int* __restrict__ goff, const int* __restrict__ gbsums,
                         unsigned* __restrict__ tmp, int E, int NBK, int BLK) {
    __shared__ int off[512];
    int t = threadIdx.x, b = blockIdx.x;
    for (int i = t; i < NBK; i += 256) {
        size_t m = (size_t)i * BLK + b;
        off[i] = goff[m] + gbsums[m >> 8];
    }
    __syncthreads();
    int base = b * EPB;
    #pragma unroll
    for (int i = 0; i < 16; ++i) {
        int e = base + i * 256 + t;
        if (e < E) {
            int d = dst[e];
            int p = atomicAdd(&off[d >> BKSH], 1);   // LDS-local
            tmp[p] = ((unsigned)src[e] << 8) | (unsigned)(d & 255);
        }
    }
}

// ---- per-bucket: count + LDS scan -> rowptr,dinv,xd4; place ewsrc ----
__global__ void bucketAF(const unsigned* __restrict__ tmp, const int* __restrict__ goff,
                         const int* __restrict__ gbsums, const float* __restrict__ x,
                         int* __restrict__ rowptr, float* __restrict__ dinv,
                         float4* __restrict__ xd4, int* __restrict__ ewsrc,
                         int N, int NBK, int BLK, int E) {
    __shared__ int lc[256], sc[256], rbase[256];
    int b = blockIdx.x, t = threadIdx.x;
    lc[t] = 0; __syncthreads();
    size_t m0 = (size_t)b * BLK;
    int p0 = goff[m0] + gbsums[m0 >> 8];
    int p1 = E;
    if (b + 1 < NBK) { size_t m1 = (size_t)(b + 1) * BLK; p1 = goff[m1] + gbsums[m1 >> 8]; }
    for (int p = p0 + t; p < p1; p += 256) atomicAdd(&lc[tmp[p] & 255u], 1);
    __syncthreads();
    int v = lc[t];
    sc[t] = v; __syncthreads();
    for (int off = 1; off < 256; off <<= 1) {
        int tv = (t >= off) ? sc[t - off] : 0;
        __syncthreads();
        sc[t] += tv;
        __syncthreads();
    }
    int rb = p0 + (sc[t] - v);
    rbase[t] = rb;
    int node = (b << BKSH) + t;
    if (node < N) {
        rowptr[node] = rb;
        float dvv = rsqrtf((float)(v + 1));
        dinv[node] = dvv;
        xd4[node]  = make_float4(dvv * x[3*node], dvv * x[3*node+1],
                                 dvv * x[3*node+2], 0.f);
    }
    if (b == 0 && t == 0) rowptr[N] = E;
    lc[t] = 0;                        // reuse as fill counters
    __syncthreads();
    for (int p = p0 + t; p < p1; p += 256) {   // 2nd read: L2-hot
        unsigned e = tmp[p];
        int dl = (int)(e & 255u);
        int pos = rbase[dl] + atomicAdd(&lc[dl], 1);
        ewsrc[pos] = (int)(e >> 8);
    }
}

// ---- a1[n] = {dinv*(sum xd[s] + xd[n]), dinv}; + fold_head in block 0 ----
__global__ void agg3w(const int* __restrict__ ewsrc, const int* __restrict__ rowptr,
                      const float* __restrict__ dinv, const float4* __restrict__ xd4,
                      float4* __restrict__ a1,
                      const float* __restrict__ W3, const float* __restrict__ b3,
                      const float* __restrict__ Wh, const float* __restrict__ bh,
                      float* __restrict__ wc, int N) {
    if (blockIdx.x == 0 && threadIdx.x < 64) {     // folded head (wc precompute)
        int k = threadIdx.x;
        float accw = 0.f;
        for (int f = 0; f < 64; f++) accw += W3[k*64+f] * Wh[f];
        wc[k] = accw;
        if (k == 0) {
            float bb = bh[0];
            for (int f = 0; f < 64; f++) bb += b3[f] * Wh[f];
            wc[64] = bb;
        }
    }
    int g   = (blockIdx.x * blockDim.x + threadIdx.x) >> 4;
    int sub = threadIdx.x & 15;
    if (g >= N) return;
    int p0 = rowptr[g], p1 = rowptr[g+1];
    float ax = 0.f, ay = 0.f, az = 0.f;
    for (int p = p0 + sub; p < p1; p += 16) {
        float4 xs = xd4[ewsrc[p]];
        ax += xs.x; ay += xs.y; az += xs.z;
    }
    #pragma unroll
    for (int off = 8; off; off >>= 1) {
        ax += __shfl_down(ax, off, 16);
        ay += __shfl_down(ay, off, 16);
        az += __shfl_down(az, off, 16);
    }
    if (sub == 0) {
        float dv = dinv[g];
        float4 xn = xd4[g];
        a1[g] = make_float4(dv * (ax + xn.x), dv * (ay + xn.y),
                            dv * (az + xn.z), dv);
    }
}

// zz[n] = dinv_n * relu( a2 @ W2 + b2 ) @ wc,
//   a2 = dinv_n*(dinv_n*relu(h1_n) + sum dinv_s*relu(h1_s)).
// STAGE-ALL-THEN-CONSUME.
__global__ void fused_l2l3(const int* __restrict__ ewsrc, const int* __restrict__ rowptr,
                           const float4* __restrict__ a1, const float* __restrict__ W1,
                           const float* __restrict__ b1, const float* __restrict__ W2,
                           const float* __restrict__ b2, const float* __restrict__ wc,
                           float* __restrict__ zz, int N, int E) {
    __shared__ float  Wl[64*64];
    __shared__ float4 pay[4][PAYCAP];
    __shared__ float  a2buf[4][64];
    const int tid = threadIdx.x;
    for (int i = tid; i < 4096; i += 256) Wl[i] = W2[i];
    const int lane = tid & 63;
    const int wv   = tid >> 6;
    const float w10 = W1[lane], w11 = W1[64+lane], w12 = W1[128+lane];
    const float b1f = b1[lane], b2f = b2[lane], wcf = wc[lane];
    const int NPW = 8;
    const int n0 = (blockIdx.x * 4 + wv) * NPW;
    int   rpl = rowptr[min(n0 + lane, N)];         // lanes 0..8 used
    float4 sg = a1[min(n0 + lane, N - 1)];         // lanes 0..7 (self; .w=dinv)
    __syncthreads();
    if (n0 >= N) return;                           // after barrier: safe
    int NPWv = N - n0; if (NPWv > NPW) NPWv = NPW; // valid nodes (SGPR)
    const int P0 = rlane_i(rpl, 0);
    const int P8 = rlane_i(rpl, NPWv);
    int span  = P8 - P0;                           // SGPR
    int stage = span < PAYCAP ? span : PAYCAP;
    // stage-all: 0-3 fully-utilized gathers, issued back-to-back
    for (int w = 0; w < stage; w += 64) {
        int idx = w + lane;
        if (idx < stage) pay[wv][idx] = a1[ewsrc[P0 + idx]];
    }
    for (int cur = 0; cur < NPWv; ++cur) {
        int p0 = rlane_i(rpl, cur);
        int p1 = rlane_i(rpl, cur + 1);
        // self term
        float sx = rlane(sg.x, cur), sy = rlane(sg.y, cur);
        float sz2 = rlane(sg.z, cur), sw = rlane(sg.w, cur);   // sw = dinv_d
        float ts = fmaf(sz2, w12, fmaf(sy, w11, fmaf(sx, w10, b1f)));
        float acc0 = sw * fmaxf(ts, 0.f);
        float acc1 = 0.f, acc2 = 0.f, acc3 = 0.f;
        // consume staged portion (uniform ds_read_b128 broadcast)
        {
            int js  = p0 - P0;
            int jse = p1 - P0; if (jse > stage) jse = stage;
            const float4* pp = (const float4*)&pay[wv][0];
            int j = js;
            for (; j + 3 < jse; j += 4) {
                float4 Q0 = pp[j], Q1 = pp[j+1], Q2 = pp[j+2], Q3 = pp[j+3];
                float t0 = fmaf(Q0.z, w12, fmaf(Q0.y, w11, fmaf(Q0.x, w10, b1f)));
                float t1 = fmaf(Q1.z, w12, fmaf(Q1.y, w11, fmaf(Q1.x, w10, b1f)));
                float t2 = fmaf(Q2.z, w12, fmaf(Q2.y, w11, fmaf(Q2.x, w10, b1f)));
                float t3 = fmaf(Q3.z, w12, fmaf(Q3.y, w11, fmaf(Q3.x, w10, b1f)));
                acc0 = fmaf(Q0.w, fmaxf(t0, 0.f), acc0);
                acc1 = fmaf(Q1.w, fmaxf(t1, 0.f), acc1);
                acc2 = fmaf(Q2.w, fmaxf(t2, 0.f), acc2);
                acc3 = fmaf(Q3.w, fmaxf(t3, 0.f), acc3);
            }
            for (; j < jse; ++j) {
                float4 Q = pp[j];
                float tt = fmaf(Q.z, w12, fmaf(Q.y, w11, fmaf(Q.x, w10, b1f)));
                acc1 = fmaf(Q.w, fmaxf(tt, 0.f), acc1);
            }
        }
        // overflow (span > PAYCAP, rare): per-chunk restage into pay[wv][0..63].
        // Safe: consume is monotonic in j; once past `stage` no later node
        // reads the staged region.
        int ov = P0 + stage; if (ov < p0) ov = p0;
        for (int pc = ov; pc < p1; pc += 64) {
            int pidx = pc + lane; if (pidx >= p1) pidx = p1 - 1;
            float4 g2 = a1[ewsrc[pidx]];
            pay[wv][lane] = g2;                    // in-order wave: prior reads done
            int m2 = p1 - pc; if (m2 > 64) m2 = 64;
            const float4* pp = (const float4*)&pay[wv][0];
            for (int jj = 0; jj < m2; ++jj) {
                float4 Q = pp[jj];
                float tt = fmaf(Q.z, w12, fmaf(Q.y, w11, fmaf(Q.x, w10, b1f)));
                acc2 = fmaf(Q.w, fmaxf(tt, 0.f), acc2);
            }
        }
        float acc = ((acc0 + acc1) + (acc2 + acc3)) * sw;      // a2 = dinv_d*(...)
        // per-node epilogue with 4 independent partials (R21 proven)
        a2buf[wv][lane] = acc;
        float ha = 0.f, hb = 0.f, hc = 0.f, hd = 0.f;
        const float4* a4 = (const float4*)&a2buf[wv][0];
        #pragma unroll
        for (int k4 = 0; k4 < 16; ++k4) {
            float4 a = a4[k4];                     // uniform broadcast read
            ha = fmaf(a.x, Wl[(4*k4+0)*64 + lane], ha);
            hb = fmaf(a.y, Wl[(4*k4+1)*64 + lane], hb);
            hc = fmaf(a.z, Wl[(4*k4+2)*64 + lane], hc);
            hd = fmaf(a.w, Wl[(4*k4+3)*64 + lane], hd);
        }
        float h = b2f + ((ha + hb) + (hc + hd));
        float v = fmaxf(h, 0.f) * wcf;
        #pragma unroll
        for (int off = 32; off; off >>= 1) v += __shfl_down(v, off);
        if (lane == 0) zz[n0 + cur] = sw * v;      // zz = dinv_n * z
    }
}

// out[d] = dinv_d*(zz[d] + sum_e zz[src]) + c; 16-lane group per node
__global__ void final_wave(const float* __restrict__ zz, const int* __restrict__ ewsrc,
                           const int* __restrict__ rowptr, const float* __restrict__ dinv,
                           const float* __restrict__ wc, float* __restrict__ out, int N) {
    int g   = (blockIdx.x * blockDim.x + threadIdx.x) >> 4;
    int sub = threadIdx.x & 15;
    if (g >= N) return;
    int p0 = rowptr[g], p1 = rowptr[g+1];
    float acc = 0.f;
    for (int p = p0 + sub; p < p1; p += 16) {
        acc += zz[ewsrc[p]];
    }
    #pragma unroll
    for (int off = 8; off; off >>= 1) acc += __shfl_down(acc, off, 16);
    if (sub == 0) {
        out[g] = fmaf(dinv[g], zz[g] + acc, wc[64]);
    }
}

extern "C" void kernel_launch(void* const* d_in, const int* in_sizes, int n_in,
                              void* d_out, int out_size, void* d_ws, size_t ws_size,
                              hipStream_t stream) {
    const float* x   = (const float*)d_in[0];
    const int*   ei  = (const int*)d_in[1];
    const float* W1  = (const float*)d_in[2];
    const float* b1  = (const float*)d_in[3];
    const float* W2  = (const float*)d_in[4];
    const float* b2  = (const float*)d_in[5];
    const float* W3  = (const float*)d_in[6];
    const float* b3  = (const float*)d_in[7];
    const float* Wh  = (const float*)d_in[8];
    const float* bh  = (const float*)d_in[9];
    float* logits = (float*)d_out;

    const int N = in_sizes[0] / 3;
    const int E = in_sizes[1] / 2;
    const int* src = ei;
    const int* dst = ei + E;

    const int NBK = (N + 255) >> BKSH;            // 391 buckets
    const int BLK = (E + EPB - 1) / EPB;          // 391 scatter blocks
    const int M   = NBK * BLK;

    float* base = (float*)d_ws;
    size_t o = 0;
    float*    dinv   = base + o; o += (size_t)N;
    o = (o + 3) & ~(size_t)3;
    float4*   a1     = (float4*)(base + o); o += (size_t)4*N;
    float4*   xd4    = (float4*)(base + o); o += (size_t)4*N;
    int*      rowptr = (int*)(base + o); o += (size_t)N + 1;
    int*      gbsums = (int*)(base + o); o += 1024;
    int*      ewsrc  = (int*)(base + o); o += (size_t)E;
    unsigned* tmpp   = (unsigned*)(base + o); o += (size_t)E;
    float*    zz     = base + o; o += (size_t)N;
    float*    wc     = base + o; o += 65;
    int*      ghist  = (int*)(base + o); o += (size_t)M;
    int*      goff   = (int*)(base + o); o += (size_t)M;

    const int BS = 256;
    int gM   = (M + BS - 1) / BS;
    int g16  = ((size_t)N * 16 + BS - 1) / BS;
    int gFU  = (N + 31) / 32;                     // 4 waves x 8 nodes per block

    bhist    <<<BLK, BS, 0, stream>>>(dst, ghist, E, NBK, BLK);
    gscan1   <<<gM,  BS, 0, stream>>>(ghist, goff, gbsums, M);
    gscan2   <<<1, 1024, 0, stream>>>(gbsums, gM);
    bscatter <<<BLK, BS, 0, stream>>>(src, dst, goff, gbsums, tmpp, E, NBK, BLK);
    bucketAF <<<NBK, BS, 0, stream>>>(tmpp, goff, gbsums, x, rowptr, dinv, xd4, ewsrc, N, NBK, BLK, E);
    agg3w    <<<g16, BS, 0, stream>>>(ewsrc, rowptr, dinv, xd4, a1, W3, b3, Wh, bh, wc, N);

    fused_l2l3 <<<gFU, BS, 0, stream>>>(ewsrc, rowptr, a1, W1, b1, W2, b2, wc, zz, N, E);
    final_wave <<<g16, BS, 0, stream>>>(zz, ewsrc, rowptr, dinv, wc, logits, N);
}